// Round 26
// baseline (61.863 us; speedup 1.0000x reference)
//
#include <hip/hip_runtime.h>

#define HID 128
#define NIN 21
#define NCLS 4

// ---- d_ws layout ----
// [0, 98304)          : G-table, 32x32 grid x 24 floats (proven r25)
// [98304, 98304+36864): packed A-fragment table (dwords)
#define GGRID 32
#define GPAD  24
#define GMIN  (-6.0f)
#define GSCALE (31.0f / 12.0f)
#define GSTEP  (12.0f / 31.0f)
#define GCLAMP 30.999f

#define A1_OFF 0
#define A2_OFF (24 * 64 * 4)
#define A3_OFF ((24 + 8) * 64 * 4)

#define L2E   1.4426950408889634f
#define L2E2  2.8853900817779268f

typedef _Float16 f16x8 __attribute__((ext_vector_type(8)));
typedef float    f32x4 __attribute__((ext_vector_type(4)));
typedef _Float16 h2_t  __attribute__((ext_vector_type(2)));
typedef unsigned u32x4 __attribute__((ext_vector_type(4)));

__device__ __forceinline__ unsigned pack_f16(float a, float b) {
    h2_t h; h.x = (_Float16)a; h.y = (_Float16)b;
    return __builtin_bit_cast(unsigned, h);
}
__device__ __forceinline__ f16x8 mk_f16x8(unsigned a, unsigned b, unsigned c, unsigned d) {
    u32x4 u; u.x = a; u.y = b; u.z = c; u.w = d;
    return __builtin_bit_cast(f16x8, u);
}
__device__ __forceinline__ float rcp_(float x)  { return __builtin_amdgcn_rcpf(x); }
__device__ __forceinline__ float exp2_(float x) { return __builtin_amdgcn_exp2f(x); }
__device__ __forceinline__ float sigmoid_pre(float gp) { return rcp_(1.0f + exp2_(-gp)); }
__device__ __forceinline__ float sigf(float x)  { return rcp_(1.0f + exp2_(-L2E * x)); }
__device__ __forceinline__ float tanhf_(float x){ return fmaf(2.0f, rcp_(1.0f + exp2_(-L2E2 * x)), -1.0f); }

// Shared-denominator LSTM h (6 trans); gi/go pre-scaled L2E, gg 2*L2E.
__device__ __forceinline__ float lstm_h(float gi, float gg, float go) {
    const float u = exp2_(-gi);
    const float v = exp2_(-gg);
    const float cn = (1.0f - v) * rcp_((1.0f + u) * (1.0f + v));
    const float w = exp2_(-go);
    const float t = exp2_(-L2E2 * cn);
    return (1.0f - t) * rcp_((1.0f + w) * (1.0f + t));
}

// ---------------- kernel 1: setup (G-table blocks 0..255, weights block 256) ----
__global__ __launch_bounds__(256)
void setup_tables(const float* __restrict__ W_ih_n,
                  const float* __restrict__ b_ih_n,
                  const float* __restrict__ b_hh_n,
                  const float* __restrict__ W_ih_e,
                  const float* __restrict__ b_ih_e,
                  const float* __restrict__ b_hh_e,
                  const float* __restrict__ W_nmpn,
                  const float* __restrict__ b_nmpn,
                  const float* __restrict__ W_fc,
                  float* __restrict__ tab,
                  unsigned* __restrict__ wtab)
{
    const int tid = threadIdx.x;
    if (blockIdx.x < 256) {
        const int lane = tid & 63;
        const int p = blockIdx.x * 4 + (tid >> 6);     // 0..1023
        const int iy = p >> 5, ix = p & 31;
        const float x0 = GMIN + (float)ix * GSTEP;
        const float x1 = GMIN + (float)iy * GSTEP;

        float he[2];
#pragma unroll
        for (int h = 0; h < 2; ++h) {
            const int d = lane + 64 * h;
            const float ei = x0 * W_ih_e[(0 * HID + d) * 2 + 0]
                           + x1 * W_ih_e[(0 * HID + d) * 2 + 1]
                           + b_ih_e[0 * HID + d] + b_hh_e[0 * HID + d];
            const float eg = x0 * W_ih_e[(2 * HID + d) * 2 + 0]
                           + x1 * W_ih_e[(2 * HID + d) * 2 + 1]
                           + b_ih_e[2 * HID + d] + b_hh_e[2 * HID + d];
            const float eo = x0 * W_ih_e[(3 * HID + d) * 2 + 0]
                           + x1 * W_ih_e[(3 * HID + d) * 2 + 1]
                           + b_ih_e[3 * HID + d] + b_hh_e[3 * HID + d];
            const float ce = sigf(ei) * tanhf_(eg);
            he[h] = sigf(eo) * tanhf_(ce);
        }
#pragma unroll
        for (int k = 0; k < NIN; ++k) {
            float s = he[0] * (L2E * W_nmpn[k * 2 * HID + lane])
                    + he[1] * (L2E * W_nmpn[k * 2 * HID + 64 + lane]);
            s += __shfl_xor(s, 1);  s += __shfl_xor(s, 2);  s += __shfl_xor(s, 4);
            s += __shfl_xor(s, 8);  s += __shfl_xor(s, 16); s += __shfl_xor(s, 32);
            if (lane == 0) tab[p * GPAD + k] = s + L2E * b_nmpn[k];
        }
        if (lane == 0) { tab[p*GPAD+21]=0.f; tab[p*GPAD+22]=0.f; tab[p*GPAD+23]=0.f; }
    } else {
        for (int idx = tid; idx < 24 * 64; idx += 256) {
            const int t = idx >> 6, ln = idx & 63;
            const int gI = t >> 3;
            const int gbase = (gI == 0) ? 0 : (gI == 1) ? 2 * HID : 3 * HID;
            const float sc = (gI == 1) ? L2E2 : L2E;
            const int row = gbase + (t & 7) * 16 + (ln & 15);
            const int k0 = (ln >> 4) * 8;
            f16x8 f;
#pragma unroll
            for (int jj = 0; jj < 8; ++jj) {
                const int k = k0 + jj;
                float v = 0.0f;
                if (k < NIN)       v = sc * W_ih_n[row * NIN + k];
                else if (k == NIN) v = sc * (b_ih_n[row] + b_hh_n[row]);
                f[jj] = (_Float16)v;
            }
            *reinterpret_cast<f16x8*>(&wtab[A1_OFF + idx * 4]) = f;
        }
        for (int idx = tid; idx < 8 * 64; idx += 256) {
            const int fr = idx >> 6, ln = idx & 63;
            const int mt = fr >> 2, kt = fr & 3;
            const int m = mt * 16 + (ln & 15);
            const int k0 = kt * 32 + (ln >> 4) * 8;
            f16x8 f;
#pragma unroll
            for (int jj = 0; jj < 8; ++jj)
                f[jj] = (m < NIN) ? (_Float16)(L2E * W_nmpn[m * 2 * HID + HID + k0 + jj])
                                  : (_Float16)0.0f;
            *reinterpret_cast<f16x8*>(&wtab[A2_OFF + idx * 4]) = f;
        }
        for (int idx = tid; idx < 4 * 64; idx += 256) {
            const int kt = idx >> 6, ln = idx & 63;
            const int m = ln & 15;
            const int k0 = kt * 32 + (ln >> 4) * 8;
            f16x8 f;
#pragma unroll
            for (int jj = 0; jj < 8; ++jj)
                f[jj] = (m < NCLS) ? (_Float16)(W_fc[m * HID + k0 + jj]) : (_Float16)0.0f;
            *reinterpret_cast<f16x8*>(&wtab[A3_OFF + idx * 4]) = f;
        }
    }
}

// ---------------- regroup: C-layout -> B-layout (verified r17-r25) ----
__device__ __forceinline__ f16x8 regroup(unsigned t0_lo, unsigned t0_hi,
                                         unsigned t1_lo, unsigned t1_hi, int lane) {
    const int g  = lane >> 4;
    const int s0 = (lane & 15) + ((g & 1) << 5);
    const int s1 = s0 + 16;
    const unsigned a0 = __shfl(t0_lo, s0), b0 = __shfl(t1_lo, s0);
    const unsigned a1 = __shfl(t0_hi, s0), b1 = __shfl(t1_hi, s0);
    const unsigned a2 = __shfl(t0_lo, s1), b2 = __shfl(t1_lo, s1);
    const unsigned a3 = __shfl(t0_hi, s1), b3 = __shfl(t1_hi, s1);
    const bool hi = g >= 2;
    return mk_f16x8(hi ? b0 : a0, hi ? b1 : a1, hi ? b2 : a2, hi ? b3 : a3);
}

#define LDA1(t)  (*reinterpret_cast<const f16x8*>(&wtab[A1_OFF + (((t) * 64 + lane) * 4)]))
#define LDA2(fr) (*reinterpret_cast<const f16x8*>(&wtab[A2_OFF + (((fr) * 64 + lane) * 4)]))
#define LDA3(kt) (*reinterpret_cast<const f16x8*>(&wtab[A3_OFF + (((kt) * 64 + lane) * 4)]))

#define GATES_H(J, BF, PLO, PHI) do {                                          \
    f32x4 ai_ = {0.0f, 0.0f, 0.0f, 0.0f};                                      \
    f32x4 ag_ = {0.0f, 0.0f, 0.0f, 0.0f};                                      \
    f32x4 ao_ = {0.0f, 0.0f, 0.0f, 0.0f};                                      \
    ai_ = __builtin_amdgcn_mfma_f32_16x16x32_f16(LDA1(J),        BF, ai_, 0, 0, 0); \
    ag_ = __builtin_amdgcn_mfma_f32_16x16x32_f16(LDA1(8 + (J)),  BF, ag_, 0, 0, 0); \
    ao_ = __builtin_amdgcn_mfma_f32_16x16x32_f16(LDA1(16 + (J)), BF, ao_, 0, 0, 0); \
    PLO = pack_f16(lstm_h(ai_[0], ag_[0], ao_[0]), lstm_h(ai_[1], ag_[1], ao_[1])); \
    PHI = pack_f16(lstm_h(ai_[2], ag_[2], ao_[2]), lstm_h(ai_[3], ag_[3], ao_[3])); \
} while (0)

__device__ __forceinline__ f16x8 make_bx(const float* __restrict__ node_feat,
                                         int nidx, int g) {
    const int k0 = g * 8;
    const float e0 = (k0     < NIN) ? node_feat[nidx * NIN + k0]     : ((k0     == NIN) ? 1.0f : 0.0f);
    const float e1 = (k0 + 1 < NIN) ? node_feat[nidx * NIN + k0 + 1] : ((k0 + 1 == NIN) ? 1.0f : 0.0f);
    const float e2 = (k0 + 2 < NIN) ? node_feat[nidx * NIN + k0 + 2] : ((k0 + 2 == NIN) ? 1.0f : 0.0f);
    const float e3 = (k0 + 3 < NIN) ? node_feat[nidx * NIN + k0 + 3] : ((k0 + 3 == NIN) ? 1.0f : 0.0f);
    const float e4 = (k0 + 4 < NIN) ? node_feat[nidx * NIN + k0 + 4] : ((k0 + 4 == NIN) ? 1.0f : 0.0f);
    const float e5 = (k0 + 5 < NIN) ? node_feat[nidx * NIN + k0 + 5] : ((k0 + 5 == NIN) ? 1.0f : 0.0f);
    const float e6 = (k0 + 6 < NIN) ? node_feat[nidx * NIN + k0 + 6] : ((k0 + 6 == NIN) ? 1.0f : 0.0f);
    const float e7 = (k0 + 7 < NIN) ? node_feat[nidx * NIN + k0 + 7] : ((k0 + 7 == NIN) ? 1.0f : 0.0f);
    return mk_f16x8(pack_f16(e0, e1), pack_f16(e2, e3),
                    pack_f16(e4, e5), pack_f16(e6, e7));
}

#define INTERP_C2(NIDX, C2A, C2B) do {                                         \
    const float xe0_ = edge_feat[(NIDX) * 2 + 0];                              \
    const float xe1_ = edge_feat[(NIDX) * 2 + 1];                              \
    const float xi_ = fminf(fmaxf((xe0_ - GMIN) * GSCALE, 0.0f), GCLAMP);      \
    const float yi_ = fminf(fmaxf((xe1_ - GMIN) * GSCALE, 0.0f), GCLAMP);      \
    const int ix_ = (int)xi_, iy_ = (int)yi_;                                  \
    const float fx_ = xi_ - (float)ix_, fy_ = yi_ - (float)iy_;                \
    const float w00_ = (1.0f - fx_) * (1.0f - fy_);                            \
    const float w01_ = fx_ * (1.0f - fy_);                                     \
    const float w10_ = (1.0f - fx_) * fy_;                                     \
    const float w11_ = fx_ * fy_;                                              \
    const float* t00_ = tab + (iy_ * GGRID + ix_) * GPAD;                      \
    const float* t01_ = t00_ + GPAD;                                           \
    const float* t10_ = t00_ + GGRID * GPAD;                                   \
    const float* t11_ = t10_ + GPAD;                                           \
    {                                                                          \
        const int ro_ = g * 4;                                                 \
        const float4 a_ = *(const float4*)(t00_ + ro_);                        \
        const float4 b_ = *(const float4*)(t01_ + ro_);                        \
        const float4 c_ = *(const float4*)(t10_ + ro_);                        \
        const float4 e_ = *(const float4*)(t11_ + ro_);                        \
        C2A[0] = w00_*a_.x + w01_*b_.x + w10_*c_.x + w11_*e_.x;                \
        C2A[1] = w00_*a_.y + w01_*b_.y + w10_*c_.y + w11_*e_.y;                \
        C2A[2] = w00_*a_.z + w01_*b_.z + w10_*c_.z + w11_*e_.z;                \
        C2A[3] = w00_*a_.w + w01_*b_.w + w10_*c_.w + w11_*e_.w;                \
    }                                                                          \
    if (g < 2) {                                                               \
        const int ro_ = 16 + g * 4;                                            \
        const float4 a_ = *(const float4*)(t00_ + ro_);                        \
        const float4 b_ = *(const float4*)(t01_ + ro_);                        \
        const float4 c_ = *(const float4*)(t10_ + ro_);                        \
        const float4 e_ = *(const float4*)(t11_ + ro_);                        \
        C2B[0] = w00_*a_.x + w01_*b_.x + w10_*c_.x + w11_*e_.x;                \
        C2B[1] = w00_*a_.y + w01_*b_.y + w10_*c_.y + w11_*e_.y;                \
        C2B[2] = w00_*a_.z + w01_*b_.z + w10_*c_.z + w11_*e_.z;                \
        C2B[3] = w00_*a_.w + w01_*b_.w + w10_*c_.w + w11_*e_.w;                \
    } else {                                                                   \
        C2B[0] = C2B[1] = C2B[2] = C2B[3] = 0.0f;                              \
    }                                                                          \
} while (0)

#define MAKE_BX2(C2A, C2B, BX2) do {                                           \
    const float s0_ = sigmoid_pre(C2A[0]);                                     \
    const float s1_ = sigmoid_pre(C2A[1]);                                     \
    const float s2_ = sigmoid_pre(C2A[2]);                                     \
    const float s3_ = sigmoid_pre(C2A[3]);                                     \
    const float s4_ = sigmoid_pre(C2B[0]);                                     \
    float s5_ = sigmoid_pre(C2B[1]);                                           \
    const float s6_ = sigmoid_pre(C2B[2]);                                     \
    const float s7_ = sigmoid_pre(C2B[3]);                                     \
    if (g == 1) s5_ = 1.0f;                                                    \
    BX2 = regroup(pack_f16(s0_, s1_), pack_f16(s2_, s3_),                      \
                  pack_f16(s4_, s5_), pack_f16(s6_, s7_), lane);               \
} while (0)

// ---------------- kernel 2: MFMA fused GNN — no LDS, 1-wave blocks ----
// r26: blocks of 64 (1 wave, 1 tile). No LDS/barrier since r21, so block size
// only sets the scheduling quantum; 1-wave blocks pack/drain CUs smoothly
// (r25 occupancy 47% despite VGPR=40 permitting 8 waves/SIMD = block-quantized
// residency). (64,4): VGPR cap 128, compiler lands ~40 (never spills).
__global__ __launch_bounds__(64, 4)
void fused_gnn_mfma(const float* __restrict__ node_feat,
                    const float* __restrict__ edge_feat,
                    const unsigned* __restrict__ wtab,
                    const float* __restrict__ b_fc,
                    const float* __restrict__ tab,
                    float* __restrict__ out,
                    int N)
{
    const int lane = threadIdx.x & 63;
    const int g    = lane >> 4;
    const int col  = lane & 15;

    const int nt = (N + 15) >> 4;
    const int tile = blockIdx.x;
    if (tile >= nt) return;

    const int node = tile * 16 + col;
    const int nidx = (node < N) ? node : (N - 1);

    const f16x8 BX = make_bx(node_feat, nidx, g);

    f32x4 C2a, C2b;
    INTERP_C2(nidx, C2a, C2b);

    // ================= iteration 1 =================
#pragma unroll
    for (int kp = 0; kp < 4; ++kp) {
        unsigned l0, h0, l1, h1;
        GATES_H(2 * kp,     BX, l0, h0);
        GATES_H(2 * kp + 1, BX, l1, h1);
        const f16x8 B2 = regroup(l0, h0, l1, h1, lane);
        C2a = __builtin_amdgcn_mfma_f32_16x16x32_f16(LDA2(kp),     B2, C2a, 0, 0, 0);
        C2b = __builtin_amdgcn_mfma_f32_16x16x32_f16(LDA2(4 + kp), B2, C2b, 0, 0, 0);
    }

    f16x8 BX2;
    MAKE_BX2(C2a, C2b, BX2);

    // ================= iteration 2 =================
    f32x4 C3;
    C3[0] = (g == 0) ? b_fc[0] : 0.0f;
    C3[1] = (g == 0) ? b_fc[1] : 0.0f;
    C3[2] = (g == 0) ? b_fc[2] : 0.0f;
    C3[3] = (g == 0) ? b_fc[3] : 0.0f;
#pragma unroll
    for (int kp = 0; kp < 4; ++kp) {
        unsigned l0, h0, l1, h1;
        GATES_H(2 * kp,     BX2, l0, h0);
        GATES_H(2 * kp + 1, BX2, l1, h1);
        const f16x8 B3 = regroup(l0, h0, l1, h1, lane);
        C3 = __builtin_amdgcn_mfma_f32_16x16x32_f16(LDA3(kp), B3, C3, 0, 0, 0);
    }

    // ================= log_softmax (lanes 0..15) ================
    if (g == 0) {
        const float lg0 = C3[0], lg1 = C3[1], lg2 = C3[2], lg3 = C3[3];
        const float mx = fmaxf(fmaxf(lg0, lg1), fmaxf(lg2, lg3));
        const float s = exp2_(L2E * (lg0 - mx)) + exp2_(L2E * (lg1 - mx))
                      + exp2_(L2E * (lg2 - mx)) + exp2_(L2E * (lg3 - mx));
        const float lse = __logf(s) + mx;
        if (node < N) {
            float4 o4;
            o4.x = lg0 - lse; o4.y = lg1 - lse;
            o4.z = lg2 - lse; o4.w = lg3 - lse;
            *reinterpret_cast<float4*>(&out[node * NCLS]) = o4;
        }
    }
}

extern "C" void kernel_launch(void* const* d_in, const int* in_sizes, int n_in,
                              void* d_out, int out_size, void* d_ws, size_t ws_size,
                              hipStream_t stream)
{
    const float* node_feat = (const float*)d_in[0];
    const float* edge_feat = (const float*)d_in[1];
    const float* W_ih_n    = (const float*)d_in[4];
    const float* b_ih_n    = (const float*)d_in[6];
    const float* b_hh_n    = (const float*)d_in[7];
    const float* W_ih_e    = (const float*)d_in[8];
    const float* b_ih_e    = (const float*)d_in[10];
    const float* b_hh_e    = (const float*)d_in[11];
    const float* W_nmpn    = (const float*)d_in[12];
    const float* b_nmpn    = (const float*)d_in[13];
    const float* W_fc      = (const float*)d_in[16];
    const float* b_fc      = (const float*)d_in[17];
    float* out = (float*)d_out;

    float*    tab  = (float*)d_ws;                          // 32*32*24*4 = 98304 B
    unsigned* wtab = (unsigned*)((char*)d_ws + 98304);      // 36864 B

    const int N = in_sizes[0] / NIN;

    setup_tables<<<257, 256, 0, stream>>>(W_ih_n, b_ih_n, b_hh_n,
                                          W_ih_e, b_ih_e, b_hh_e,
                                          W_nmpn, b_nmpn, W_fc, tab, wtab);

    const int nt = (N + 15) / 16;            // 12500 tiles = 12500 one-wave blocks
    fused_gnn_mfma<<<nt, 64, 0, stream>>>(node_feat, edge_feat, wtab, b_fc,
                                          tab, out, N);
}

// Round 27
// 57.329 us; speedup vs baseline: 1.0791x; 1.0791x over previous
//
#include <hip/hip_runtime.h>

#define HID 128
#define NIN 21
#define NCLS 4

// ---- d_ws layout ----
// [0, 98304)          : G-table, 32x32 grid x 24 floats (proven r25/r26)
// [98304, 98304+36864): packed A-fragment table (dwords)
#define GGRID 32
#define GPAD  24
#define GMIN  (-6.0f)
#define GSCALE (31.0f / 12.0f)
#define GSTEP  (12.0f / 31.0f)
#define GCLAMP 30.999f

#define A1_OFF 0
#define A2_OFF (24 * 64 * 4)
#define A3_OFF ((24 + 8) * 64 * 4)

#define L2E   1.4426950408889634f
#define L2E2  2.8853900817779268f

// r27: K-permutation pi(g,j) = g*4 + (j&3) + 16*(j>>2), bijective on 0..31.
// With A-columns staged under pi and B built under pi, each lane's B-slots
// coincide with the C-output values it already holds (C row m = g*4+r /
// 16+g*4+r) -> the 8-shfl regroup (64 ds_bpermute/tile, the kernel's ONLY
// LDS traffic) vanishes. MFMA sums over K, so a consistent K-permutation
// is mathematically exact.
#define KPERM(G, J) ((G) * 4 + ((J) & 3) + 16 * ((J) >> 2))

typedef _Float16 f16x8 __attribute__((ext_vector_type(8)));
typedef float    f32x4 __attribute__((ext_vector_type(4)));
typedef _Float16 h2_t  __attribute__((ext_vector_type(2)));
typedef unsigned u32x4 __attribute__((ext_vector_type(4)));

__device__ __forceinline__ unsigned pack_f16(float a, float b) {
    h2_t h; h.x = (_Float16)a; h.y = (_Float16)b;
    return __builtin_bit_cast(unsigned, h);
}
__device__ __forceinline__ f16x8 mk_f16x8(unsigned a, unsigned b, unsigned c, unsigned d) {
    u32x4 u; u.x = a; u.y = b; u.z = c; u.w = d;
    return __builtin_bit_cast(f16x8, u);
}
__device__ __forceinline__ float rcp_(float x)  { return __builtin_amdgcn_rcpf(x); }
__device__ __forceinline__ float exp2_(float x) { return __builtin_amdgcn_exp2f(x); }
__device__ __forceinline__ float sigmoid_pre(float gp) { return rcp_(1.0f + exp2_(-gp)); }
__device__ __forceinline__ float sigf(float x)  { return rcp_(1.0f + exp2_(-L2E * x)); }
__device__ __forceinline__ float tanhf_(float x){ return fmaf(2.0f, rcp_(1.0f + exp2_(-L2E2 * x)), -1.0f); }

// Shared-denominator LSTM h (6 trans); gi/go pre-scaled L2E, gg 2*L2E.
__device__ __forceinline__ float lstm_h(float gi, float gg, float go) {
    const float u = exp2_(-gi);
    const float v = exp2_(-gg);
    const float cn = (1.0f - v) * rcp_((1.0f + u) * (1.0f + v));
    const float w = exp2_(-go);
    const float t = exp2_(-L2E2 * cn);
    return (1.0f - t) * rcp_((1.0f + w) * (1.0f + t));
}

// ---------------- kernel 1: setup (G-table blocks 0..255, weights block 256) ----
__global__ __launch_bounds__(256)
void setup_tables(const float* __restrict__ W_ih_n,
                  const float* __restrict__ b_ih_n,
                  const float* __restrict__ b_hh_n,
                  const float* __restrict__ W_ih_e,
                  const float* __restrict__ b_ih_e,
                  const float* __restrict__ b_hh_e,
                  const float* __restrict__ W_nmpn,
                  const float* __restrict__ b_nmpn,
                  const float* __restrict__ W_fc,
                  float* __restrict__ tab,
                  unsigned* __restrict__ wtab)
{
    const int tid = threadIdx.x;
    if (blockIdx.x < 256) {
        const int lane = tid & 63;
        const int p = blockIdx.x * 4 + (tid >> 6);     // 0..1023
        const int iy = p >> 5, ix = p & 31;
        const float x0 = GMIN + (float)ix * GSTEP;
        const float x1 = GMIN + (float)iy * GSTEP;

        float he[2];
#pragma unroll
        for (int h = 0; h < 2; ++h) {
            const int d = lane + 64 * h;
            const float ei = x0 * W_ih_e[(0 * HID + d) * 2 + 0]
                           + x1 * W_ih_e[(0 * HID + d) * 2 + 1]
                           + b_ih_e[0 * HID + d] + b_hh_e[0 * HID + d];
            const float eg = x0 * W_ih_e[(2 * HID + d) * 2 + 0]
                           + x1 * W_ih_e[(2 * HID + d) * 2 + 1]
                           + b_ih_e[2 * HID + d] + b_hh_e[2 * HID + d];
            const float eo = x0 * W_ih_e[(3 * HID + d) * 2 + 0]
                           + x1 * W_ih_e[(3 * HID + d) * 2 + 1]
                           + b_ih_e[3 * HID + d] + b_hh_e[3 * HID + d];
            const float ce = sigf(ei) * tanhf_(eg);
            he[h] = sigf(eo) * tanhf_(ce);
        }
#pragma unroll
        for (int k = 0; k < NIN; ++k) {
            float s = he[0] * (L2E * W_nmpn[k * 2 * HID + lane])
                    + he[1] * (L2E * W_nmpn[k * 2 * HID + 64 + lane]);
            s += __shfl_xor(s, 1);  s += __shfl_xor(s, 2);  s += __shfl_xor(s, 4);
            s += __shfl_xor(s, 8);  s += __shfl_xor(s, 16); s += __shfl_xor(s, 32);
            if (lane == 0) tab[p * GPAD + k] = s + L2E * b_nmpn[k];
        }
        if (lane == 0) { tab[p*GPAD+21]=0.f; tab[p*GPAD+22]=0.f; tab[p*GPAD+23]=0.f; }
    } else {
        // ---- A1: 24 tiles (0-7 gi, 8-15 gg, 16-23 go); columns pi-permuted;
        //      bias at feature 21 ----
        for (int idx = tid; idx < 24 * 64; idx += 256) {
            const int t = idx >> 6, ln = idx & 63;
            const int gI = t >> 3;
            const int gbase = (gI == 0) ? 0 : (gI == 1) ? 2 * HID : 3 * HID;
            const float sc = (gI == 1) ? L2E2 : L2E;
            const int row = gbase + (t & 7) * 16 + (ln & 15);
            const int g = ln >> 4;
            f16x8 f;
#pragma unroll
            for (int jj = 0; jj < 8; ++jj) {
                const int k = KPERM(g, jj);
                float v = 0.0f;
                if (k < NIN)       v = sc * W_ih_n[row * NIN + k];
                else if (k == NIN) v = sc * (b_ih_n[row] + b_hh_n[row]);
                f[jj] = (_Float16)v;
            }
            *reinterpret_cast<f16x8*>(&wtab[A1_OFF + idx * 4]) = f;
        }
        // ---- A2: fr = mt*4 + kt; columns d = kt*32 + pi(g,jj) ----
        for (int idx = tid; idx < 8 * 64; idx += 256) {
            const int fr = idx >> 6, ln = idx & 63;
            const int mt = fr >> 2, kt = fr & 3;
            const int m = mt * 16 + (ln & 15);
            const int g = ln >> 4;
            f16x8 f;
#pragma unroll
            for (int jj = 0; jj < 8; ++jj) {
                const int d = kt * 32 + KPERM(g, jj);
                f[jj] = (m < NIN) ? (_Float16)(L2E * W_nmpn[m * 2 * HID + HID + d])
                                  : (_Float16)0.0f;
            }
            *reinterpret_cast<f16x8*>(&wtab[A2_OFF + idx * 4]) = f;
        }
        // ---- A3: columns d = kt*32 + pi(g,jj) ----
        for (int idx = tid; idx < 4 * 64; idx += 256) {
            const int kt = idx >> 6, ln = idx & 63;
            const int m = ln & 15;
            const int g = ln >> 4;
            f16x8 f;
#pragma unroll
            for (int jj = 0; jj < 8; ++jj) {
                const int d = kt * 32 + KPERM(g, jj);
                f[jj] = (m < NCLS) ? (_Float16)(W_fc[m * HID + d]) : (_Float16)0.0f;
            }
            *reinterpret_cast<f16x8*>(&wtab[A3_OFF + idx * 4]) = f;
        }
    }
}

#define LDA1(t)  (*reinterpret_cast<const f16x8*>(&wtab[A1_OFF + (((t) * 64 + lane) * 4)]))
#define LDA2(fr) (*reinterpret_cast<const f16x8*>(&wtab[A2_OFF + (((fr) * 64 + lane) * 4)]))
#define LDA3(kt) (*reinterpret_cast<const f16x8*>(&wtab[A3_OFF + (((kt) * 64 + lane) * 4)]))

#define GATES_H(J, BF, PLO, PHI) do {                                          \
    f32x4 ai_ = {0.0f, 0.0f, 0.0f, 0.0f};                                      \
    f32x4 ag_ = {0.0f, 0.0f, 0.0f, 0.0f};                                      \
    f32x4 ao_ = {0.0f, 0.0f, 0.0f, 0.0f};                                      \
    ai_ = __builtin_amdgcn_mfma_f32_16x16x32_f16(LDA1(J),        BF, ai_, 0, 0, 0); \
    ag_ = __builtin_amdgcn_mfma_f32_16x16x32_f16(LDA1(8 + (J)),  BF, ag_, 0, 0, 0); \
    ao_ = __builtin_amdgcn_mfma_f32_16x16x32_f16(LDA1(16 + (J)), BF, ao_, 0, 0, 0); \
    PLO = pack_f16(lstm_h(ai_[0], ag_[0], ao_[0]), lstm_h(ai_[1], ag_[1], ao_[1])); \
    PHI = pack_f16(lstm_h(ai_[2], ag_[2], ao_[2]), lstm_h(ai_[3], ag_[3], ao_[3])); \
} while (0)

// B_X fragment under pi: slot jj carries feature KPERM(g,jj); 1.0 at 21 (bias).
__device__ __forceinline__ f16x8 make_bx(const float* __restrict__ node_feat,
                                         int nidx, int g) {
    float e[8];
#pragma unroll
    for (int jj = 0; jj < 8; ++jj) {
        const int k = KPERM(g, jj);
        e[jj] = (k < NIN) ? node_feat[nidx * NIN + k] : ((k == NIN) ? 1.0f : 0.0f);
    }
    return mk_f16x8(pack_f16(e[0], e[1]), pack_f16(e[2], e[3]),
                    pack_f16(e[4], e[5]), pack_f16(e[6], e[7]));
}

#define INTERP_C2(NIDX, C2A, C2B) do {                                         \
    const float xe0_ = edge_feat[(NIDX) * 2 + 0];                              \
    const float xe1_ = edge_feat[(NIDX) * 2 + 1];                              \
    const float xi_ = fminf(fmaxf((xe0_ - GMIN) * GSCALE, 0.0f), GCLAMP);      \
    const float yi_ = fminf(fmaxf((xe1_ - GMIN) * GSCALE, 0.0f), GCLAMP);      \
    const int ix_ = (int)xi_, iy_ = (int)yi_;                                  \
    const float fx_ = xi_ - (float)ix_, fy_ = yi_ - (float)iy_;                \
    const float w00_ = (1.0f - fx_) * (1.0f - fy_);                            \
    const float w01_ = fx_ * (1.0f - fy_);                                     \
    const float w10_ = (1.0f - fx_) * fy_;                                     \
    const float w11_ = fx_ * fy_;                                              \
    const float* t00_ = tab + (iy_ * GGRID + ix_) * GPAD;                      \
    const float* t01_ = t00_ + GPAD;                                           \
    const float* t10_ = t00_ + GGRID * GPAD;                                   \
    const float* t11_ = t10_ + GPAD;                                           \
    {                                                                          \
        const int ro_ = g * 4;                                                 \
        const float4 a_ = *(const float4*)(t00_ + ro_);                        \
        const float4 b_ = *(const float4*)(t01_ + ro_);                        \
        const float4 c_ = *(const float4*)(t10_ + ro_);                        \
        const float4 e_ = *(const float4*)(t11_ + ro_);                        \
        C2A[0] = w00_*a_.x + w01_*b_.x + w10_*c_.x + w11_*e_.x;                \
        C2A[1] = w00_*a_.y + w01_*b_.y + w10_*c_.y + w11_*e_.y;                \
        C2A[2] = w00_*a_.z + w01_*b_.z + w10_*c_.z + w11_*e_.z;                \
        C2A[3] = w00_*a_.w + w01_*b_.w + w10_*c_.w + w11_*e_.w;                \
    }                                                                          \
    if (g < 2) {                                                               \
        const int ro_ = 16 + g * 4;                                            \
        const float4 a_ = *(const float4*)(t00_ + ro_);                        \
        const float4 b_ = *(const float4*)(t01_ + ro_);                        \
        const float4 c_ = *(const float4*)(t10_ + ro_);                        \
        const float4 e_ = *(const float4*)(t11_ + ro_);                        \
        C2B[0] = w00_*a_.x + w01_*b_.x + w10_*c_.x + w11_*e_.x;                \
        C2B[1] = w00_*a_.y + w01_*b_.y + w10_*c_.y + w11_*e_.y;                \
        C2B[2] = w00_*a_.z + w01_*b_.z + w10_*c_.z + w11_*e_.z;                \
        C2B[3] = w00_*a_.w + w01_*b_.w + w10_*c_.w + w11_*e_.w;                \
    } else {                                                                   \
        C2B[0] = C2B[1] = C2B[2] = C2B[3] = 0.0f;                              \
    }                                                                          \
} while (0)

// xn1 = sigmoid(C2): under pi, lane's C2 registers ARE its B-slots directly.
// k=21 (bias) sits at slot (g=1, j=5) = C2B[1] when g==1 -> force 1.0.
#define MAKE_BX2(C2A, C2B, BX2) do {                                           \
    const float s0_ = sigmoid_pre(C2A[0]);                                     \
    const float s1_ = sigmoid_pre(C2A[1]);                                     \
    const float s2_ = sigmoid_pre(C2A[2]);                                     \
    const float s3_ = sigmoid_pre(C2A[3]);                                     \
    const float s4_ = sigmoid_pre(C2B[0]);                                     \
    float s5_ = sigmoid_pre(C2B[1]);                                           \
    const float s6_ = sigmoid_pre(C2B[2]);                                     \
    const float s7_ = sigmoid_pre(C2B[3]);                                     \
    if (g == 1) s5_ = 1.0f;                                                    \
    BX2 = mk_f16x8(pack_f16(s0_, s1_), pack_f16(s2_, s3_),                     \
                   pack_f16(s4_, s5_), pack_f16(s6_, s7_));                    \
} while (0)

// ---------------- kernel 2: MFMA fused GNN — no LDS, no shuffles ----
__global__ __launch_bounds__(64, 4)
void fused_gnn_mfma(const float* __restrict__ node_feat,
                    const float* __restrict__ edge_feat,
                    const unsigned* __restrict__ wtab,
                    const float* __restrict__ b_fc,
                    const float* __restrict__ tab,
                    float* __restrict__ out,
                    int N)
{
    const int lane = threadIdx.x & 63;
    const int g    = lane >> 4;
    const int col  = lane & 15;

    const int nt = (N + 15) >> 4;
    const int tile = blockIdx.x;
    if (tile >= nt) return;

    const int node = tile * 16 + col;
    const int nidx = (node < N) ? node : (N - 1);

    const f16x8 BX = make_bx(node_feat, nidx, g);

    f32x4 C2a, C2b;
    INTERP_C2(nidx, C2a, C2b);

    // ================= iteration 1 =================
#pragma unroll
    for (int kp = 0; kp < 4; ++kp) {
        unsigned l0, h0, l1, h1;
        GATES_H(2 * kp,     BX, l0, h0);
        GATES_H(2 * kp + 1, BX, l1, h1);
        const f16x8 B2 = mk_f16x8(l0, h0, l1, h1);   // pi-aligned: no regroup
        C2a = __builtin_amdgcn_mfma_f32_16x16x32_f16(LDA2(kp),     B2, C2a, 0, 0, 0);
        C2b = __builtin_amdgcn_mfma_f32_16x16x32_f16(LDA2(4 + kp), B2, C2b, 0, 0, 0);
    }

    f16x8 BX2;
    MAKE_BX2(C2a, C2b, BX2);

    // ================= iteration 2 =================
    f32x4 C3;
    C3[0] = (g == 0) ? b_fc[0] : 0.0f;
    C3[1] = (g == 0) ? b_fc[1] : 0.0f;
    C3[2] = (g == 0) ? b_fc[2] : 0.0f;
    C3[3] = (g == 0) ? b_fc[3] : 0.0f;
#pragma unroll
    for (int kp = 0; kp < 4; ++kp) {
        unsigned l0, h0, l1, h1;
        GATES_H(2 * kp,     BX2, l0, h0);
        GATES_H(2 * kp + 1, BX2, l1, h1);
        const f16x8 B3 = mk_f16x8(l0, h0, l1, h1);
        C3 = __builtin_amdgcn_mfma_f32_16x16x32_f16(LDA3(kp), B3, C3, 0, 0, 0);
    }

    // ================= log_softmax (lanes 0..15) ================
    if (g == 0) {
        const float lg0 = C3[0], lg1 = C3[1], lg2 = C3[2], lg3 = C3[3];
        const float mx = fmaxf(fmaxf(lg0, lg1), fmaxf(lg2, lg3));
        const float s = exp2_(L2E * (lg0 - mx)) + exp2_(L2E * (lg1 - mx))
                      + exp2_(L2E * (lg2 - mx)) + exp2_(L2E * (lg3 - mx));
        const float lse = __logf(s) + mx;
        if (node < N) {
            float4 o4;
            o4.x = lg0 - lse; o4.y = lg1 - lse;
            o4.z = lg2 - lse; o4.w = lg3 - lse;
            *reinterpret_cast<float4*>(&out[node * NCLS]) = o4;
        }
    }
}

extern "C" void kernel_launch(void* const* d_in, const int* in_sizes, int n_in,
                              void* d_out, int out_size, void* d_ws, size_t ws_size,
                              hipStream_t stream)
{
    const float* node_feat = (const float*)d_in[0];
    const float* edge_feat = (const float*)d_in[1];
    const float* W_ih_n    = (const float*)d_in[4];
    const float* b_ih_n    = (const float*)d_in[6];
    const float* b_hh_n    = (const float*)d_in[7];
    const float* W_ih_e    = (const float*)d_in[8];
    const float* b_ih_e    = (const float*)d_in[10];
    const float* b_hh_e    = (const float*)d_in[11];
    const float* W_nmpn    = (const float*)d_in[12];
    const float* b_nmpn    = (const float*)d_in[13];
    const float* W_fc      = (const float*)d_in[16];
    const float* b_fc      = (const float*)d_in[17];
    float* out = (float*)d_out;

    float*    tab  = (float*)d_ws;                          // 98304 B
    unsigned* wtab = (unsigned*)((char*)d_ws + 98304);      // 36864 B

    const int N = in_sizes[0] / NIN;

    setup_tables<<<257, 256, 0, stream>>>(W_ih_n, b_ih_n, b_hh_n,
                                          W_ih_e, b_ih_e, b_hh_e,
                                          W_nmpn, b_nmpn, W_fc, tab, wtab);

    const int nt = (N + 15) / 16;            // 12500 tiles = 12500 one-wave blocks
    fused_gnn_mfma<<<nt, 64, 0, stream>>>(node_feat, edge_feat, wtab, b_fc,
                                          tab, out, N);
}